// Round 9
// baseline (640.306 us; speedup 1.0000x reference)
//
#include <hip/hip_runtime.h>
#include <hip/hip_bf16.h>

#define N_NODES 100000
#define N_EDGES 3200000
#define SHIFT 9            // 512 rows per coarse bucket
#define NBC 196            // ceil(100000 / 512)
#define CAP 18000          // per-bucket capacity (mean 16327, 13 sigma)
#define CAP_ROW 80         // per-row slot capacity (mean 32, P(>80)~1e-6)
#define EPB 4096           // edges per split block
#define NSPLIT 782         // ceil(N_EDGES / EPB)
#define NGEMM 1563         // ceil(N_NODES / 64)

typedef __attribute__((ext_vector_type(8))) short short8;
typedef __attribute__((ext_vector_type(4))) float f32x4;

__device__ inline short bfbits(float x) {
    __hip_bfloat16 h = __float2bfloat16(x);
    return __builtin_bit_cast(short, h);
}

__device__ inline short8 load_cvt8(const float* __restrict__ p) {
    float4 a = *(const float4*)p;
    float4 b = *(const float4*)(p + 4);
    short8 r;
    r[0] = bfbits(a.x); r[1] = bfbits(a.y); r[2] = bfbits(a.z); r[3] = bfbits(a.w);
    r[4] = bfbits(b.x); r[5] = bfbits(b.y); r[6] = bfbits(b.z); r[7] = bfbits(b.w);
    return r;
}

__device__ inline int block_excl_scan_256(int c, int* wsum, int& total) {
    const int lane = threadIdx.x & 63, wid = threadIdx.x >> 6;
    int v = c;
    #pragma unroll
    for (int off = 1; off < 64; off <<= 1) {
        int u = __shfl_up(v, off);
        if (lane >= off) v += u;
    }
    if (lane == 63) wsum[wid] = v;
    __syncthreads();
    int w0 = wsum[0], w1 = wsum[1], w2 = wsum[2], w3 = wsum[3];
    total = w0 + w1 + w2 + w3;
    int wex = (wid > 0 ? w0 : 0) + (wid > 1 ? w1 : 0) + (wid > 2 ? w2 : 0);
    return wex + v - c;
}

// ======================= shared device bodies ==============================

__device__ void do_split(int bid,
    const int* __restrict__ rows, const int* __restrict__ cols,
    const float* __restrict__ vals, int* __restrict__ gcursor,
    int2* __restrict__ bcv, int nE)
{
    __shared__ int cnt[256];
    __shared__ int startp[256];
    __shared__ int posp[256];
    __shared__ int gb[256];
    __shared__ int wsum[4];
    __shared__ int2 scv[EPB];
    const int t  = threadIdx.x;
    const int e0 = bid * EPB;

    cnt[t] = 0;
    __syncthreads();

    int  myb[16];
    int2 mycv[16];
    #pragma unroll
    for (int k = 0; k < 16; ++k) {
        int e = e0 + k * 256 + t;
        if (e < nE) {
            int r = rows[e];
            myb[k]  = r >> SHIFT;
            mycv[k] = make_int2(((r & 511) << 17) | cols[e],
                                __float_as_int(vals[e]));
            atomicAdd(&cnt[myb[k]], 1);
        } else {
            myb[k] = -1;
        }
    }
    __syncthreads();

    int c = cnt[t];
    int total;
    int ex = block_excl_scan_256(c, wsum, total);
    startp[t] = ex;
    posp[t]   = ex;
    if (t < NBC && c) gb[t] = atomicAdd(&gcursor[t], c);
    __syncthreads();

    #pragma unroll
    for (int k = 0; k < 16; ++k) {
        if (myb[k] >= 0) {
            int p = atomicAdd(&posp[myb[k]], 1);
            scv[p] = mycv[k];
        }
    }
    __syncthreads();

    const int lane = t & 63, wid = t >> 6;
    for (int b = wid; b < NBC; b += 4) {
        int cb = cnt[b];
        if (!cb) continue;
        int st = startp[b], g = gb[b];
        int lim = (b + 1) * CAP;          // safety clamp (never hit)
        if (g + cb > lim) cb = lim > g ? lim - g : 0;
        for (int i = lane; i < cb; i += 64)
            bcv[g + i] = scv[st + i];
    }
}

__device__ void do_gemm(int bid,
    const float* __restrict__ X, const float* __restrict__ W,
    unsigned short* __restrict__ Y)
{
    const int wid  = threadIdx.x >> 6;
    const int lane = threadIdx.x & 63;
    const int m0   = bid * 64;
    const int n0   = wid * 64;
    const int lr   = lane & 15;
    const int ko   = (lane >> 4) * 8;
    const int M    = N_NODES;

    f32x4 acc[4][4] = {};

    #pragma unroll
    for (int k0 = 0; k0 < 256; k0 += 32) {
        short8 bfrag[4], afrag[4];
        #pragma unroll
        for (int j = 0; j < 4; ++j)
            bfrag[j] = load_cvt8(W + (size_t)(n0 + j * 16 + lr) * 256 + k0 + ko);
        #pragma unroll
        for (int i = 0; i < 4; ++i) {
            int r = m0 + i * 16 + lr;
            if (r > M - 1) r = M - 1;
            afrag[i] = load_cvt8(X + (size_t)r * 256 + k0 + ko);
        }
        #pragma unroll
        for (int i = 0; i < 4; ++i)
            #pragma unroll
            for (int j = 0; j < 4; ++j)
                acc[i][j] = __builtin_amdgcn_mfma_f32_16x16x32_bf16(
                    afrag[i], bfrag[j], acc[i][j], 0, 0, 0);
    }

    #pragma unroll
    for (int i = 0; i < 4; ++i) {
        int rbase = m0 + i * 16 + (lane >> 4) * 4;
        #pragma unroll
        for (int rr = 0; rr < 4; ++rr) {
            int r = rbase + rr;
            if (r < M) {
                #pragma unroll
                for (int j = 0; j < 4; ++j)
                    Y[(size_t)r * 256 + n0 + j * 16 + lr] =
                        (unsigned short)bfbits(acc[i][j][rr]);
            }
        }
    }
}

// gather inner loop: accumulate row's edges from cedge[s..e) and store H[row].
__device__ void gather_core(
    const unsigned short* __restrict__ Y, const int2* __restrict__ cedge,
    float* __restrict__ H, int row, int s, int e, int lane)
{
    float4 acc = make_float4(0.f, 0.f, 0.f, 0.f);
    const int fo = lane * 4;

    for (int base = s; base < e; base += 64) {
        int idx = base + lane;
        int2 q = make_int2(0, 0);
        if (idx < e) q = cedge[idx];
        int cnt = min(64, e - base);
        int j = 0;
        for (; j + 4 <= cnt; j += 4) {
            int c0 = __builtin_amdgcn_readfirstlane(__shfl(q.x, j))     & 0x1FFFF;
            int c1 = __builtin_amdgcn_readfirstlane(__shfl(q.x, j + 1)) & 0x1FFFF;
            int c2 = __builtin_amdgcn_readfirstlane(__shfl(q.x, j + 2)) & 0x1FFFF;
            int c3 = __builtin_amdgcn_readfirstlane(__shfl(q.x, j + 3)) & 0x1FFFF;
            float v0 = __int_as_float(__builtin_amdgcn_readfirstlane(__shfl(q.y, j)));
            float v1 = __int_as_float(__builtin_amdgcn_readfirstlane(__shfl(q.y, j + 1)));
            float v2 = __int_as_float(__builtin_amdgcn_readfirstlane(__shfl(q.y, j + 2)));
            float v3 = __int_as_float(__builtin_amdgcn_readfirstlane(__shfl(q.y, j + 3)));
            ushort4 y0 = *(const ushort4*)(Y + (size_t)c0 * 256 + fo);
            ushort4 y1 = *(const ushort4*)(Y + (size_t)c1 * 256 + fo);
            ushort4 y2 = *(const ushort4*)(Y + (size_t)c2 * 256 + fo);
            ushort4 y3 = *(const ushort4*)(Y + (size_t)c3 * 256 + fo);
            acc.x += __uint_as_float((unsigned)y0.x << 16) * v0;
            acc.y += __uint_as_float((unsigned)y0.y << 16) * v0;
            acc.z += __uint_as_float((unsigned)y0.z << 16) * v0;
            acc.w += __uint_as_float((unsigned)y0.w << 16) * v0;
            acc.x += __uint_as_float((unsigned)y1.x << 16) * v1;
            acc.y += __uint_as_float((unsigned)y1.y << 16) * v1;
            acc.z += __uint_as_float((unsigned)y1.z << 16) * v1;
            acc.w += __uint_as_float((unsigned)y1.w << 16) * v1;
            acc.x += __uint_as_float((unsigned)y2.x << 16) * v2;
            acc.y += __uint_as_float((unsigned)y2.y << 16) * v2;
            acc.z += __uint_as_float((unsigned)y2.z << 16) * v2;
            acc.w += __uint_as_float((unsigned)y2.w << 16) * v2;
            acc.x += __uint_as_float((unsigned)y3.x << 16) * v3;
            acc.y += __uint_as_float((unsigned)y3.y << 16) * v3;
            acc.z += __uint_as_float((unsigned)y3.z << 16) * v3;
            acc.w += __uint_as_float((unsigned)y3.w << 16) * v3;
        }
        for (; j < cnt; ++j) {
            int   cj = __builtin_amdgcn_readfirstlane(__shfl(q.x, j)) & 0x1FFFF;
            float vj = __int_as_float(__builtin_amdgcn_readfirstlane(__shfl(q.y, j)));
            ushort4 y4 = *(const ushort4*)(Y + (size_t)cj * 256 + fo);
            acc.x += __uint_as_float((unsigned)y4.x << 16) * vj;
            acc.y += __uint_as_float((unsigned)y4.y << 16) * vj;
            acc.z += __uint_as_float((unsigned)y4.z << 16) * vj;
            acc.w += __uint_as_float((unsigned)y4.w << 16) * vj;
        }
    }
    float4 r;
    r.x = acc.x > 0.f ? acc.x : 0.f;
    r.y = acc.y > 0.f ? acc.y : 0.f;
    r.z = acc.z > 0.f ? acc.z : 0.f;
    r.w = acc.w > 0.f ? acc.w : 0.f;
    ((float4*)(H + (size_t)row * 256))[lane] = r;
}

// ============================== kernels ====================================

__global__ __launch_bounds__(256) void init_cursor(int* __restrict__ gcursor)
{
    int t = threadIdx.x;
    if (t < NBC) gcursor[t] = t * CAP;
}

// -------- primary path --------

__global__ __launch_bounds__(256) void split_gemm(
    const int* __restrict__ rows, const int* __restrict__ cols,
    const float* __restrict__ vals, int* __restrict__ gcursor,
    int2* __restrict__ bcv,
    const float* __restrict__ X, const float* __restrict__ W,
    unsigned short* __restrict__ Y, int nE)
{
    if (blockIdx.x < NSPLIT)
        do_split(blockIdx.x, rows, cols, vals, gcursor, bcv, nE);
    else
        do_gemm(blockIdx.x - NSPLIT, X, W, Y);
}

// one pass: bcv (bucket-grouped) -> per-row capacity slots in cedge
__global__ __launch_bounds__(256) void row_scatter(
    const int* __restrict__ gcursor, const int2* __restrict__ bcv,
    int* __restrict__ rowcur, int2* __restrict__ cedge)
{
    const int b  = blockIdx.x >> 3;
    const int s8 = blockIdx.x & 7;
    const int s  = b * CAP;
    int e = gcursor[b];
    int lim = s + CAP;
    if (e > lim) e = lim;
    for (int j = s + s8 * 256 + threadIdx.x; j < e; j += 8 * 256) {
        int2 q = bcv[j];
        int r = (b << SHIFT) | ((unsigned)q.x >> 17);
        int p = atomicAdd(&rowcur[r], 1);
        if (p < CAP_ROW)
            cedge[(size_t)r * CAP_ROW + p] = q;
    }
}

__global__ __launch_bounds__(256) void spmm_gather_slot(
    const unsigned short* __restrict__ Y,
    const int* __restrict__ rowcur, const int2* __restrict__ cedge,
    float* __restrict__ H)
{
    int row  = blockIdx.x * 4 + (threadIdx.x >> 6);
    int lane = threadIdx.x & 63;
    if (row >= N_NODES) return;
    int s = row * CAP_ROW;
    int deg = rowcur[row];
    if (deg > CAP_ROW) deg = CAP_ROW;
    gather_core(Y, cedge, H, row, s, s + deg, lane);
}

// -------- fallback path (R8) --------

__global__ __launch_bounds__(256) void bucket_split(
    const int* __restrict__ rows, const int* __restrict__ cols,
    const float* __restrict__ vals, int* __restrict__ gcursor,
    int2* __restrict__ bcv, int nE)
{
    do_split(blockIdx.x, rows, cols, vals, gcursor, bcv, nE);
}

__global__ __launch_bounds__(256) void csr_gemm(
    const int* __restrict__ gcursor, const int2* __restrict__ bcv,
    int* __restrict__ rs, int* __restrict__ re, int2* __restrict__ cedge,
    const float* __restrict__ X, const float* __restrict__ W,
    unsigned short* __restrict__ Y)
{
    if (blockIdx.x < NBC) {
        __shared__ int hist[512];
        __shared__ int cur[512];
        __shared__ int wsum[4];
        const int t = threadIdx.x;
        const int b = blockIdx.x;
        const int s = b * CAP, e = gcursor[b];
        const int r0 = b << SHIFT;

        hist[t] = 0; hist[t + 256] = 0;
        __syncthreads();
        for (int j = s + t; j < e; j += 256)
            atomicAdd(&hist[(unsigned)bcv[j].x >> 17], 1);
        __syncthreads();

        int c0 = hist[2 * t], c1 = hist[2 * t + 1];
        int total;
        int ex = block_excl_scan_256(c0 + c1, wsum, total);
        cur[2 * t]     = s + ex;
        cur[2 * t + 1] = s + ex + c0;
        int r = r0 + 2 * t;
        if (r < N_NODES)     { rs[r]     = s + ex;      re[r]     = s + ex + c0; }
        if (r + 1 < N_NODES) { rs[r + 1] = s + ex + c0; re[r + 1] = s + ex + c0 + c1; }
        __syncthreads();

        for (int j = s + t; j < e; j += 256) {
            int2 q = bcv[j];
            int p = atomicAdd(&cur[(unsigned)q.x >> 17], 1);
            cedge[p] = q;
        }
    } else {
        do_gemm(blockIdx.x - NBC, X, W, Y);
    }
}

__global__ __launch_bounds__(256) void spmm_gather_rsre(
    const unsigned short* __restrict__ Y,
    const int* __restrict__ rs, const int* __restrict__ re,
    const int2* __restrict__ cedge,
    float* __restrict__ H)
{
    int row  = blockIdx.x * 4 + (threadIdx.x >> 6);
    int lane = threadIdx.x & 63;
    if (row >= N_NODES) return;
    gather_core(Y, cedge, H, row, rs[row], re[row], lane);
}

// ===========================================================================

extern "C" void kernel_launch(void* const* d_in, const int* in_sizes, int n_in,
                              void* d_out, int out_size, void* d_ws, size_t ws_size,
                              hipStream_t stream) {
    const float* X    = (const float*)d_in[0];
    const int*   rows = (const int*)d_in[1];
    const int*   cols = (const int*)d_in[2];
    const float* vals = (const float*)d_in[3];
    const float* W    = (const float*)d_in[4];
    float*       H    = (float*)d_out;
    char*        ws   = (char*)d_ws;

    // Primary layout:
    //   Y       @           0 : 51,200,000  bf16 [N,256]
    //   bcv     @  51,200,000 : 28,224,000  int2 [NBC*CAP]
    //   cedge   @  79,424,000 : 64,000,000  int2 [N*CAP_ROW]
    //   rowcur  @ 143,424,000 :    400,128  int [N]
    //   gcursor @ 143,824,128 :      1,024  int [NBC]
    const size_t NEEDED = 143825152;

    unsigned short* Y   = (unsigned short*)(ws);
    int2*           bcv = (int2*)(ws + 51200000);

    if (ws_size >= NEEDED) {
        int2* cedge   = (int2*)(ws + 79424000);
        int*  rowcur  = (int*)(ws + 143424000);
        int*  gcursor = (int*)(ws + 143824128);

        hipMemsetAsync(rowcur, 0, (size_t)N_NODES * sizeof(int), stream);
        init_cursor<<<1, 256, 0, stream>>>(gcursor);
        split_gemm<<<NSPLIT + NGEMM, 256, 0, stream>>>(
            rows, cols, vals, gcursor, bcv, X, W, Y, N_EDGES);
        row_scatter<<<NBC * 8, 256, 0, stream>>>(gcursor, bcv, rowcur, cedge);
        spmm_gather_slot<<<(N_NODES + 3) / 4, 256, 0, stream>>>(Y, rowcur, cedge, H);
    } else {
        // R8 layout/path
        int2* cedge   = (int2*)(ws + 79424000);
        int*  rs      = (int*)(ws + 107648000);
        int*  re      = (int*)(ws + 108048128);
        int*  gcursor = (int*)(ws + 108448256);

        init_cursor<<<1, 256, 0, stream>>>(gcursor);
        bucket_split<<<NSPLIT, 256, 0, stream>>>(rows, cols, vals, gcursor, bcv, N_EDGES);
        csr_gemm<<<NBC + NGEMM, 256, 0, stream>>>(gcursor, bcv, rs, re, cedge, X, W, Y);
        spmm_gather_rsre<<<(N_NODES + 3) / 4, 256, 0, stream>>>(Y, rs, re, cedge, H);
    }
}

// Round 10
// 414.764 us; speedup vs baseline: 1.5438x; 1.5438x over previous
//
#include <hip/hip_runtime.h>
#include <hip/hip_bf16.h>

#define N_NODES 100000
#define N_EDGES 3200000
#define SHIFT 9            // 512 rows per coarse bucket
#define NBC 196            // ceil(100000 / 512)
#define CAP 18000          // per-bucket capacity (mean 16327, 13 sigma)
#define EPB 4096           // edges per split block
#define NSPLIT 782         // ceil(N_EDGES / EPB)
#define NGEMM 1563         // ceil(N_NODES / 64)

typedef __attribute__((ext_vector_type(8))) short short8;
typedef __attribute__((ext_vector_type(4))) float f32x4;

__device__ inline short bfbits(float x) {
    __hip_bfloat16 h = __float2bfloat16(x);
    return __builtin_bit_cast(short, h);
}

__device__ inline short8 load_cvt8(const float* __restrict__ p) {
    float4 a = *(const float4*)p;
    float4 b = *(const float4*)(p + 4);
    short8 r;
    r[0] = bfbits(a.x); r[1] = bfbits(a.y); r[2] = bfbits(a.z); r[3] = bfbits(a.w);
    r[4] = bfbits(b.x); r[5] = bfbits(b.y); r[6] = bfbits(b.z); r[7] = bfbits(b.w);
    return r;
}

__device__ inline int block_excl_scan_256(int c, int* wsum, int& total) {
    const int lane = threadIdx.x & 63, wid = threadIdx.x >> 6;
    int v = c;
    #pragma unroll
    for (int off = 1; off < 64; off <<= 1) {
        int u = __shfl_up(v, off);
        if (lane >= off) v += u;
    }
    if (lane == 63) wsum[wid] = v;
    __syncthreads();
    int w0 = wsum[0], w1 = wsum[1], w2 = wsum[2], w3 = wsum[3];
    total = w0 + w1 + w2 + w3;
    int wex = (wid > 0 ? w0 : 0) + (wid > 1 ? w1 : 0) + (wid > 2 ? w2 : 0);
    return wex + v - c;
}

// ===================== 1) bucket split (LDS-staged scatter) ================
// Stage EPB edges bucket-grouped in LDS (payload (row_local<<17)|col, val;
// bucket id in sbkt). Copy-out is flat over all staged edges: every lane
// active, consecutive i within a bucket run -> coalesced global writes.
// gcursor[b] counts from 0 (dst base = b*CAP + old) so host memset(0) works.
__global__ __launch_bounds__(256) void bucket_split(
    const int* __restrict__ rows, const int* __restrict__ cols,
    const float* __restrict__ vals, int* __restrict__ gcursor,
    int2* __restrict__ bcv, int nE)
{
    __shared__ int cnt[256];
    __shared__ int startp[256];
    __shared__ int posp[256];
    __shared__ int gb[256];
    __shared__ int wsum[4];
    __shared__ int2 scv[EPB];
    __shared__ unsigned short sbkt[EPB];
    const int t  = threadIdx.x;
    const int e0 = blockIdx.x * EPB;

    cnt[t] = 0;
    __syncthreads();

    int  myb[16];
    int2 mycv[16];
    #pragma unroll
    for (int k = 0; k < 16; ++k) {
        int e = e0 + k * 256 + t;
        if (e < nE) {
            int r = rows[e];
            myb[k]  = r >> SHIFT;
            mycv[k] = make_int2(((r & 511) << 17) | cols[e],
                                __float_as_int(vals[e]));
            atomicAdd(&cnt[myb[k]], 1);
        } else {
            myb[k] = -1;
        }
    }
    __syncthreads();

    int c = cnt[t];
    int total;
    int ex = block_excl_scan_256(c, wsum, total);
    startp[t] = ex;
    posp[t]   = ex;
    if (t < NBC && c) gb[t] = t * CAP + atomicAdd(&gcursor[t], c);
    __syncthreads();

    #pragma unroll
    for (int k = 0; k < 16; ++k) {
        if (myb[k] >= 0) {
            int p = atomicAdd(&posp[myb[k]], 1);
            scv[p]  = mycv[k];
            sbkt[p] = (unsigned short)myb[k];
        }
    }
    __syncthreads();

    for (int i = t; i < total; i += 256) {
        int bk  = sbkt[i];
        int dst = gb[bk] + (i - startp[bk]);
        if (dst < (bk + 1) * CAP)          // 13-sigma overflow guard
            bcv[dst] = scv[i];
    }
}

// ============ 2) merged: per-bucket counting sort  ||  GEMM ================
// Blocks [0, NBC): counting-sort bucket b's edges by row_local; emit per-row
// [rs, re) and row-grouped cedge (still packed; gather masks col).
// Blocks [NBC, ...): bf16 MFMA GEMM  Y = X @ W^T  (64 rows/block).
__global__ __launch_bounds__(256) void csr_gemm(
    const int* __restrict__ gcursor, const int2* __restrict__ bcv,
    int* __restrict__ rs, int* __restrict__ re, int2* __restrict__ cedge,
    const float* __restrict__ X, const float* __restrict__ W,
    unsigned short* __restrict__ Y)
{
    if (blockIdx.x < NBC) {
        __shared__ int hist[512];
        __shared__ int cur[512];
        __shared__ int wsum[4];
        const int t = threadIdx.x;
        const int b = blockIdx.x;
        const int s = b * CAP;
        int n = gcursor[b];
        if (n > CAP) n = CAP;
        const int e = s + n;
        const int r0 = b << SHIFT;

        hist[t] = 0; hist[t + 256] = 0;
        __syncthreads();
        for (int j = s + t; j < e; j += 256)
            atomicAdd(&hist[(unsigned)bcv[j].x >> 17], 1);
        __syncthreads();

        int c0 = hist[2 * t], c1 = hist[2 * t + 1];
        int total;
        int ex = block_excl_scan_256(c0 + c1, wsum, total);
        cur[2 * t]     = s + ex;
        cur[2 * t + 1] = s + ex + c0;
        int r = r0 + 2 * t;
        if (r < N_NODES)     { rs[r]     = s + ex;      re[r]     = s + ex + c0; }
        if (r + 1 < N_NODES) { rs[r + 1] = s + ex + c0; re[r + 1] = s + ex + c0 + c1; }
        __syncthreads();

        for (int j = s + t; j < e; j += 256) {
            int2 q = bcv[j];
            int p = atomicAdd(&cur[(unsigned)q.x >> 17], 1);
            cedge[p] = q;
        }
    } else {
        const int bid  = blockIdx.x - NBC;
        const int wid  = threadIdx.x >> 6;
        const int lane = threadIdx.x & 63;
        const int m0   = bid * 64;
        const int n0   = wid * 64;
        const int lr   = lane & 15;
        const int ko   = (lane >> 4) * 8;
        const int M    = N_NODES;

        f32x4 acc[4][4] = {};

        #pragma unroll
        for (int k0 = 0; k0 < 256; k0 += 32) {
            short8 bfrag[4], afrag[4];
            #pragma unroll
            for (int j = 0; j < 4; ++j)
                bfrag[j] = load_cvt8(W + (size_t)(n0 + j * 16 + lr) * 256 + k0 + ko);
            #pragma unroll
            for (int i = 0; i < 4; ++i) {
                int r = m0 + i * 16 + lr;
                if (r > M - 1) r = M - 1;
                afrag[i] = load_cvt8(X + (size_t)r * 256 + k0 + ko);
            }
            #pragma unroll
            for (int i = 0; i < 4; ++i)
                #pragma unroll
                for (int j = 0; j < 4; ++j)
                    acc[i][j] = __builtin_amdgcn_mfma_f32_16x16x32_bf16(
                        afrag[i], bfrag[j], acc[i][j], 0, 0, 0);
        }

        #pragma unroll
        for (int i = 0; i < 4; ++i) {
            int rbase = m0 + i * 16 + (lane >> 4) * 4;
            #pragma unroll
            for (int rr = 0; rr < 4; ++rr) {
                int r = rbase + rr;
                if (r < M) {
                    #pragma unroll
                    for (int j = 0; j < 4; ++j)
                        Y[(size_t)r * 256 + n0 + j * 16 + lr] =
                            (unsigned short)bfbits(acc[i][j][rr]);
                }
            }
        }
    }
}

// =================== 3) Gather SpMM:  H = relu(A @ Y) ======================
// One wave per row; lane l owns features [4l,4l+4). 4-wide edge unroll.
__global__ __launch_bounds__(256) void spmm_gather_relu(
    const unsigned short* __restrict__ Y,
    const int* __restrict__ rs, const int* __restrict__ re,
    const int2* __restrict__ cedge,
    float* __restrict__ H)
{
    int row  = blockIdx.x * 4 + (threadIdx.x >> 6);
    int lane = threadIdx.x & 63;
    if (row >= N_NODES) return;
    int s = rs[row];
    int e = re[row];

    float4 acc = make_float4(0.f, 0.f, 0.f, 0.f);
    const int fo = lane * 4;

    for (int base = s; base < e; base += 64) {
        int idx = base + lane;
        int2 q = make_int2(0, 0);
        if (idx < e) q = cedge[idx];
        int cnt = min(64, e - base);
        int j = 0;
        for (; j + 4 <= cnt; j += 4) {
            int c0 = __builtin_amdgcn_readfirstlane(__shfl(q.x, j))     & 0x1FFFF;
            int c1 = __builtin_amdgcn_readfirstlane(__shfl(q.x, j + 1)) & 0x1FFFF;
            int c2 = __builtin_amdgcn_readfirstlane(__shfl(q.x, j + 2)) & 0x1FFFF;
            int c3 = __builtin_amdgcn_readfirstlane(__shfl(q.x, j + 3)) & 0x1FFFF;
            float v0 = __int_as_float(__builtin_amdgcn_readfirstlane(__shfl(q.y, j)));
            float v1 = __int_as_float(__builtin_amdgcn_readfirstlane(__shfl(q.y, j + 1)));
            float v2 = __int_as_float(__builtin_amdgcn_readfirstlane(__shfl(q.y, j + 2)));
            float v3 = __int_as_float(__builtin_amdgcn_readfirstlane(__shfl(q.y, j + 3)));
            ushort4 y0 = *(const ushort4*)(Y + (size_t)c0 * 256 + fo);
            ushort4 y1 = *(const ushort4*)(Y + (size_t)c1 * 256 + fo);
            ushort4 y2 = *(const ushort4*)(Y + (size_t)c2 * 256 + fo);
            ushort4 y3 = *(const ushort4*)(Y + (size_t)c3 * 256 + fo);
            acc.x += __uint_as_float((unsigned)y0.x << 16) * v0;
            acc.y += __uint_as_float((unsigned)y0.y << 16) * v0;
            acc.z += __uint_as_float((unsigned)y0.z << 16) * v0;
            acc.w += __uint_as_float((unsigned)y0.w << 16) * v0;
            acc.x += __uint_as_float((unsigned)y1.x << 16) * v1;
            acc.y += __uint_as_float((unsigned)y1.y << 16) * v1;
            acc.z += __uint_as_float((unsigned)y1.z << 16) * v1;
            acc.w += __uint_as_float((unsigned)y1.w << 16) * v1;
            acc.x += __uint_as_float((unsigned)y2.x << 16) * v2;
            acc.y += __uint_as_float((unsigned)y2.y << 16) * v2;
            acc.z += __uint_as_float((unsigned)y2.z << 16) * v2;
            acc.w += __uint_as_float((unsigned)y2.w << 16) * v2;
            acc.x += __uint_as_float((unsigned)y3.x << 16) * v3;
            acc.y += __uint_as_float((unsigned)y3.y << 16) * v3;
            acc.z += __uint_as_float((unsigned)y3.z << 16) * v3;
            acc.w += __uint_as_float((unsigned)y3.w << 16) * v3;
        }
        for (; j < cnt; ++j) {
            int   cj = __builtin_amdgcn_readfirstlane(__shfl(q.x, j)) & 0x1FFFF;
            float vj = __int_as_float(__builtin_amdgcn_readfirstlane(__shfl(q.y, j)));
            ushort4 y4 = *(const ushort4*)(Y + (size_t)cj * 256 + fo);
            acc.x += __uint_as_float((unsigned)y4.x << 16) * vj;
            acc.y += __uint_as_float((unsigned)y4.y << 16) * vj;
            acc.z += __uint_as_float((unsigned)y4.z << 16) * vj;
            acc.w += __uint_as_float((unsigned)y4.w << 16) * vj;
        }
    }
    float4 r;
    r.x = acc.x > 0.f ? acc.x : 0.f;
    r.y = acc.y > 0.f ? acc.y : 0.f;
    r.z = acc.z > 0.f ? acc.z : 0.f;
    r.w = acc.w > 0.f ? acc.w : 0.f;
    ((float4*)(H + (size_t)row * 256))[lane] = r;
}

// ===========================================================================

extern "C" void kernel_launch(void* const* d_in, const int* in_sizes, int n_in,
                              void* d_out, int out_size, void* d_ws, size_t ws_size,
                              hipStream_t stream) {
    const float* X    = (const float*)d_in[0];
    const int*   rows = (const int*)d_in[1];
    const int*   cols = (const int*)d_in[2];
    const float* vals = (const float*)d_in[3];
    const float* W    = (const float*)d_in[4];
    float*       H    = (float*)d_out;
    char*        ws   = (char*)d_ws;

    // Workspace layout (256-aligned):
    //   Y       @           0 : 51,200,000  bf16 [N,256]
    //   bcv     @  51,200,000 : 28,224,000  int2 [NBC*CAP] bucket-grouped
    //   cedge   @  79,424,000 : 28,224,000  int2 [NBC*CAP] row-sorted
    //   rs      @ 107,648,000 :    400,128  int [N]
    //   re      @ 108,048,128 :    400,128  int [N]
    //   gcursor @ 108,448,256 :      1,024  int [NBC]  (counts, memset 0)
    unsigned short* Y       = (unsigned short*)(ws);
    int2*           bcv     = (int2*)(ws + 51200000);
    int2*           cedge   = (int2*)(ws + 79424000);
    int*            rs      = (int*)(ws + 107648000);
    int*            re      = (int*)(ws + 108048128);
    int*            gcursor = (int*)(ws + 108448256);

    hipMemsetAsync(gcursor, 0, NBC * sizeof(int), stream);
    bucket_split<<<NSPLIT, 256, 0, stream>>>(rows, cols, vals, gcursor, bcv, N_EDGES);
    csr_gemm<<<NBC + NGEMM, 256, 0, stream>>>(gcursor, bcv, rs, re, cedge, X, W, Y);
    spmm_gather_relu<<<(N_NODES + 3) / 4, 256, 0, stream>>>(Y, rs, re, cedge, H);
}